// Round 2
// baseline (799.330 us; speedup 1.0000x reference)
//
#include <hip/hip_runtime.h>

#define TPB 256
#define NW 4
#define NPTS 2000
#define M1C 100
#define M2C 5
#define KNN 20
#define CANDCAP 128   // knn scratch cap (knn1 cn<=~30 typ, knn2 cn<=100)
#define PCH 32        // producer chunks: 32*64 = 2048 >= 2000

typedef float v2f __attribute__((ext_vector_type(2)));

// Bitwise-exact squared distance matching numpy fp32 sequential sum:
// ((dx*dx + dy*dy) + dz*dz), no FMA contraction.
__device__ __forceinline__ float dist3(float px, float py, float pz,
                                       float qx, float qy, float qz) {
#pragma clang fp contract(off)
    float dx = px - qx, dy = py - qy, dz = pz - qz;
    return dx * dx + dy * dy + dz * dz;
}

// Packed pair variant: identical per-component op order (sub,mul,add,add),
// so each component is bitwise identical to dist3.
__device__ __forceinline__ v2f dist3p(v2f px, v2f py, v2f pz, v2f q0, v2f q1, v2f q2) {
#pragma clang fp contract(off)
    v2f dx = px - q0, dy = py - q1, dz = pz - q2;
    v2f ax = dx * dx;
    v2f ay = dy * dy;
    v2f az = dz * dz;
    return (ax + ay) + az;
}

// Fused wave64 (value,index) argmax, min-index tie-break, DPP chain.
#define ARGMAX_STEP(ctrl, rm)                                                        \
    do {                                                                             \
        float ov = __int_as_float(__builtin_amdgcn_update_dpp(                       \
            (int)0xff800000, __float_as_int(v), ctrl, rm, 0xf, false));              \
        int oi = __builtin_amdgcn_update_dpp(0x7fffffff, i, ctrl, rm, 0xf, false);   \
        bool take = (ov > v) || (ov == v && oi < i);                                 \
        v = take ? ov : v;                                                           \
        i = take ? oi : i;                                                           \
    } while (0)

__device__ __forceinline__ void wave_argmax(float& v, int& i) {
    ARGMAX_STEP(0x111, 0xf);
    ARGMAX_STEP(0x112, 0xf);
    ARGMAX_STEP(0x114, 0xf);
    ARGMAX_STEP(0x118, 0xf);
    ARGMAX_STEP(0x142, 0xa);
    ARGMAX_STEP(0x143, 0xc);
    v = __int_as_float(__builtin_amdgcn_readlane(__float_as_int(v), 63));
    i = __builtin_amdgcn_readlane(i, 63);
}

#define FMAX_STEP(ctrl, rm)                                                          \
    do {                                                                             \
        float _t = __int_as_float(__builtin_amdgcn_update_dpp(                       \
            (int)0xff800000, __float_as_int(x), ctrl, rm, 0xf, false));              \
        x = fmaxf(x, _t);                                                            \
    } while (0)

__device__ __forceinline__ float wave_fmax(float x) {
    FMAX_STEP(0x111, 0xf);
    FMAX_STEP(0x112, 0xf);
    FMAX_STEP(0x114, 0xf);
    FMAX_STEP(0x118, 0xf);
    FMAX_STEP(0x142, 0xa);
    FMAX_STEP(0x143, 0xc);
    return __int_as_float(__builtin_amdgcn_readlane(__float_as_int(x), 63));
}

// ============ Fused kernel ============
// R13: SINGLE-WAVE FPS1 producer, zero cross-wave sync in the FPS loop.
// R12 post-mortem showed producer per-iteration latency passes 1:1 into total
// time and the 4-wave argmax/atomic/spin sync machinery costs ~2000 cyc/iter
// vs ~300 cyc of actual compute. Wave 0 now holds all 2000 points in
// registers (16x v2f per coord), does dist+min (160 packed ops), an
// in-register 31-node tree argmax, one DPP wave_argmax, one uniform LDS read
// for the next query — then publishes smp[it] + a release-stored progress
// counter. TPB=256 => 4 waves, one per SIMD: producer gets a private SIMD
// (no issue contention), waves 1-3 are R11-style knn1/MLP1 consumers
// (pace: ~1800 cyc/sample needed vs 3*T_prod ≈ 2250 available).
__global__ __launch_bounds__(TPB, 1) void fused_kernel(
    const float* __restrict__ P,
    const float* __restrict__ W1, const float* __restrict__ b1,
    const float* __restrict__ W2, const float* __restrict__ b2,
    const float* __restrict__ W3, const float* __restrict__ b3,
    const float* __restrict__ D1, const float* __restrict__ bD1,
    const float* __restrict__ D2, const float* __restrict__ bD2,
    const float* __restrict__ D3, const float* __restrict__ bD3,
    float* __restrict__ out)
{
    __shared__ float sx[NPTS], sy[NPTS], sz[NPTS];
    __shared__ float smpx[M1C], smpy[M1C], smpz[M1C];
    __shared__ float s2x[M2C], s2y[M2C], s2z[M2C];
    __shared__ float f1s[M1C][5];
    __shared__ float knd[NW][CANDCAP];
    __shared__ int   kni[NW][CANDCAP];
    __shared__ float vin[M2C][KNN][8];     // knn2 valid-candidate inputs
    __shared__ int prog;                   // highest published FPS1 sample index
    __shared__ float f2s[M2C][25];
    __shared__ float latent[45];
    __shared__ float decv[M2C][3];
    __shared__ float cfs[M2C][25];
    __shared__ float dec2s[M1C][3];
    __shared__ float cf2s[M1C][5];
    __shared__ float w2s[200], b2s[25], w3s[1260], b3s[45];

    const int b = blockIdx.x;
    const int tid = threadIdx.x;
    const int lane = tid & 63;
    const int wid = tid >> 6;

    const float R1SQ = (float)(0.3 * 0.3);   // f64 product then cast
    const float R2SQ = 1.0f;
    const float INVR1 = 1.0f / 0.3f;

    // ---- staging (all 4 waves) ----
    const float* Pb = P + (size_t)b * (NPTS * 3);
    for (int j = tid; j < NPTS; j += TPB) {
        sx[j] = Pb[3 * j + 0];
        sy[j] = Pb[3 * j + 1];
        sz[j] = Pb[3 * j + 2];
    }
    for (int t = tid; t < 200; t += TPB) w2s[t] = W2[t];
    for (int t = tid; t < 25; t += TPB) b2s[t] = b2[t];
    for (int t = tid; t < 1260; t += TPB) w3s[t] = W3[t];
    for (int t = tid; t < 45; t += TPB) b3s[t] = b3[t];
    if (tid == 0) prog = -1;
    __syncthreads();

    if (wid == 0) {
        // ================= producer: single-wave FPS1 =================
        // chunk k covers points [k*64, k*64+64); j = k*64 + lane is the
        // true linear point index, so (value,index) argmax with min-index
        // tie-break replicates jnp.argmax first-occurrence semantics.
        v2f px2[16], py2[16], pz2[16], mind2[16];
#pragma unroll
        for (int p = 0; p < 16; ++p) {
#pragma unroll
            for (int h = 0; h < 2; ++h) {
                int k = 2 * p + h;
                int j = k * 64 + lane;
                bool v = j < NPTS;
                int jc = v ? j : 0;
                px2[p][h] = v ? sx[jc] : 1e18f;
                py2[p][h] = v ? sy[jc] : 1e18f;
                pz2[p][h] = v ? sz[jc] : 1e18f;
                mind2[p][h] = v ? 1e10f : -1.0f;
            }
        }

        float qx = sx[0], qy = sy[0], qz = sz[0];
        for (int it = 0; it < M1C; ++it) {
            if (lane == 0) {
                smpx[it] = qx; smpy[it] = qy; smpz[it] = qz;
                __hip_atomic_store(&prog, it, __ATOMIC_RELEASE,
                                   __HIP_MEMORY_SCOPE_WORKGROUP);
            }
            if (it == M1C - 1) break;   // last sample: no further argmax needed

            v2f q0 = {qx, qx}, q1 = {qy, qy}, q2 = {qz, qz};
            float v[PCH]; int ki[PCH];
#pragma unroll
            for (int p = 0; p < 16; ++p) {
                v2f d = dist3p(px2[p], py2[p], pz2[p], q0, q1, q2);
                v2f mm;
                mm[0] = fminf(mind2[p][0], d[0]);
                mm[1] = fminf(mind2[p][1], d[1]);
                mind2[p] = mm;
                v[2 * p] = mm[0];
                v[2 * p + 1] = mm[1];
                ki[2 * p] = 2 * p;
                ki[2 * p + 1] = 2 * p + 1;
            }
            // in-register tree argmax over 32 chunks; strict > keeps lowest chunk
#pragma unroll
            for (int step = 1; step < PCH; step <<= 1) {
#pragma unroll
                for (int k = 0; k + step < PCH; k += 2 * step) {
                    bool t = v[k + step] > v[k];
                    v[k]  = t ? v[k + step] : v[k];
                    ki[k] = t ? ki[k + step] : ki[k];
                }
            }
            float bv = v[0];
            int bi = (ki[0] << 6) | lane;   // = linear point index
            wave_argmax(bv, bi);            // broadcast (value,index), min-idx ties
            qx = sx[bi]; qy = sy[bi]; qz = sz[bi];   // uniform addr -> broadcast read
        }

        // ---- FPS2: 5 from 100 (same wave, in-LDS smp) ----
        {
            float ax = smpx[lane], ay = smpy[lane], az = smpz[lane];
            bool vb2 = lane < (M1C - 64);
            float bx2 = vb2 ? smpx[lane + 64] : 1e18f;
            float by2 = vb2 ? smpy[lane + 64] : 1e18f;
            float bz2 = vb2 ? smpz[lane + 64] : 1e18f;
            float m2a = 1e10f;
            float m2b = vb2 ? 1e10f : -1.0f;
            int last2 = 0;
            for (int it = 0; it < M2C; ++it) {
                float fx = smpx[last2], fy = smpy[last2], fz = smpz[last2];
                if (lane == 0) { s2x[it] = fx; s2y[it] = fy; s2z[it] = fz; }
                m2a = fminf(m2a, dist3(ax, ay, az, fx, fy, fz));
                m2b = fminf(m2b, dist3(bx2, by2, bz2, fx, fy, fz));
                float v = m2a; int i = lane;
                if (m2b > v) { v = m2b; i = lane + 64; }
                wave_argmax(v, i);
                last2 = i;
            }
        }
    } else {
        // ================= consumers: knn1 + MLP1 (waves 1-3) =================
        float rw1[15], rb1[5];
#pragma unroll
        for (int i = 0; i < 15; ++i) rw1[i] = W1[i];
#pragma unroll
        for (int i = 0; i < 5; ++i) rb1[i] = b1[i];

        for (int s = wid - 1; s < M1C; s += (NW - 1)) {
            // wait until producer published sample s
            while (__hip_atomic_load(&prog, __ATOMIC_ACQUIRE,
                                     __HIP_MEMORY_SCOPE_WORKGROUP) < s)
                __builtin_amdgcn_s_sleep(1);
            float qx = smpx[s], qy = smpy[s], qz = smpz[s];
            int cn = 0;
#pragma unroll 4
            for (int c = 0; c < 32; ++c) {
                int j = c * 64 + lane;
                float d = 0.0f; bool pred = false;
                if (j < NPTS) {
                    d = dist3(sx[j], sy[j], sz[j], qx, qy, qz);
                    pred = (d <= R1SQ);
                }
                unsigned long long mb = __ballot(pred);
                if (pred) {
                    int pos = cn + (int)__popcll(mb & ((1ull << lane) - 1ull));
                    if (pos < CANDCAP) { knd[wid][pos] = d; kni[wid][pos] = j; }
                }
                cn += (int)__popcll(mb);
            }
            if (cn > CANDCAP) cn = CANDCAP;  // P(Poisson λ≈14 > 128) ~ 1e-68
            float fmx[5];
#pragma unroll
            for (int f = 0; f < 5; ++f) fmx[f] = -1e30f;
            for (int t = lane; t < cn; t += 64) {
                float d = knd[wid][t]; int j = kni[wid][t];
                bool valid = true;
                if (cn > KNN) {
                    int rank = 0;
                    for (int u = 0; u < cn; ++u) {
                        float du = knd[wid][u]; int iu = kni[wid][u];
                        rank += (du < d || (du == d && iu < j)) ? 1 : 0;
                    }
                    valid = rank < KNN;   // replicates top_k stability (ties -> lower idx)
                }
                if (valid) {
                    float rx = (sx[j] - qx) * INVR1;
                    float ry = (sy[j] - qy) * INVR1;
                    float rz = (sz[j] - qz) * INVR1;
#pragma unroll
                    for (int f = 0; f < 5; ++f) {
                        float h = fmaf(rx, rw1[f], fmaf(ry, rw1[5 + f], fmaf(rz, rw1[10 + f], rb1[f])));
                        fmx[f] = fmaxf(fmx[f], fmaxf(h, 0.0f));
                    }
                }
            }
#pragma unroll
            for (int f = 0; f < 5; ++f) fmx[f] = wave_fmax(fmx[f]);
            if (lane == 0) {
#pragma unroll
                for (int f = 0; f < 5; ++f) f1s[s][f] = fmx[f];
            }
        }
    }
    __syncthreads();   // all 4 waves reach exactly once

    // ================= tail: knn2 + MLP2 (DPP-free), MLP3, decoder =================
    for (int s = wid; s < M2C; s += NW) {
        float qx2 = s2x[s], qy2 = s2y[s], qz2 = s2z[s];
        int cn = 0;
#pragma unroll
        for (int c = 0; c < 2; ++c) {
            int j = c * 64 + lane;
            float d = 0.0f; bool pred = false;
            if (j < M1C) {
                d = dist3(smpx[j], smpy[j], smpz[j], qx2, qy2, qz2);
                pred = (d <= R2SQ);
            }
            unsigned long long mb = __ballot(pred);
            if (pred) {
                int pos = cn + (int)__popcll(mb & ((1ull << lane) - 1ull));
                knd[wid][pos] = d; kni[wid][pos] = j;   // cn<=100<CANDCAP
            }
            cn += (int)__popcll(mb);
        }
        // build valid-candidate input vectors (order-independent for max)
        int nv = 0;
#pragma unroll
        for (int c = 0; c < 2; ++c) {
            int t = c * 64 + lane;
            bool valid = false;
            float in8[8];
            if (t < cn) {
                float d = knd[wid][t]; int j = kni[wid][t];
                valid = true;
                if (cn > KNN) {
                    int rank = 0;
                    for (int u = 0; u < cn; ++u) {
                        float du = knd[wid][u]; int iu = kni[wid][u];
                        rank += (du < d || (du == d && iu < j)) ? 1 : 0;
                    }
                    valid = rank < KNN;
                }
                if (valid) {
                    in8[0] = smpx[j] - qx2; in8[1] = smpy[j] - qy2; in8[2] = smpz[j] - qz2;
#pragma unroll
                    for (int f = 0; f < 5; ++f) in8[3 + f] = f1s[j][f];
                }
            }
            unsigned long long mb = __ballot(valid);
            if (valid) {
                int pos = nv + (int)__popcll(mb & ((1ull << lane) - 1ull));
#pragma unroll
                for (int i = 0; i < 8; ++i) vin[s][pos][i] = in8[i];   // nv<=20
            }
            nv += (int)__popcll(mb);
        }
        // feature-per-lane max (no DPP chains); nv >= 1 (sample in own ball)
        if (lane < 25) {
            float hmx = -1e30f;
            for (int c = 0; c < nv; ++c) {
                float h = b2s[lane];
#pragma unroll
                for (int i = 0; i < 8; ++i) h = fmaf(vin[s][c][i], w2s[i * 25 + lane], h);
                hmx = fmaxf(hmx, fmaxf(h, 0.0f));
            }
            f2s[s][lane] = hmx;
        }
    }
    __syncthreads();

    // ---- MLP3 + max-pool -> latent (45) ----
    if (wid == 0 && lane < 45) {
        float lm = -1e30f;
        for (int r = 0; r < M2C; ++r) {
            float h = b3s[lane];
            h = fmaf(s2x[r] * 0.5f, w3s[0 * 45 + lane], h);
            h = fmaf(s2y[r] * 0.5f, w3s[1 * 45 + lane], h);
            h = fmaf(s2z[r] * 0.5f, w3s[2 * 45 + lane], h);
#pragma unroll
            for (int i = 0; i < 25; ++i) h = fmaf(f2s[r][i], w3s[(3 + i) * 45 + lane], h);
            lm = fmaxf(lm, fmaxf(h, 0.0f));
        }
        latent[lane] = lm;
    }
    __syncthreads();

    // ---- decoder stage 1: latent @ D1 + bD1 -> (5, 28) ----
    for (int t = tid; t < 140; t += TPB) {
        float acc = bD1[t];
        for (int i = 0; i < 45; i++) acc = fmaf(latent[i], D1[i * 140 + t], acc);
        int r = t / 28, c = t % 28;
        if (c < 3) decv[r][c] = acc;
        else cfs[r][c - 3] = fmaxf(acc, 0.0f);
    }
    __syncthreads();

    // ---- decoder stage 2: cf @ D2 + bD2 -> (100, 8) ----
    for (int t = tid; t < 800; t += TPB) {
        int r = t / 160, c = t % 160;
        float acc = bD2[c];
        for (int i = 0; i < 25; i++) acc = fmaf(cfs[r][i], D2[i * 160 + c], acc);
        int g = r * 20 + c / 8, c8 = c % 8;
        if (c8 < 3) dec2s[g][c8] = acc;
        else cf2s[g][c8 - 3] = fmaxf(acc, 0.0f);
    }
    __syncthreads();

    // ---- decoder stage 3 + compose output ----
    float* outb = out + (size_t)b * (NPTS * 3);
    for (int t = tid; t < NPTS * 3; t += TPB) {
        int n = t / 3, c = t % 3;
        int g = n / 20;
        int m = n / 400;
        int r60 = (n % 20) * 3 + c;
        float acc = bD3[r60];
        for (int i = 0; i < 5; i++) acc = fmaf(cf2s[g][i], D3[i * 60 + r60], acc);
        // out = ((dec*R3 + dec2)*R2 + dec3)*R1, R2 = 1
        float val = ((decv[m][c] * 2.0f + dec2s[g][c]) + acc) * 0.3f;
        outb[t] = val;
    }
}

extern "C" void kernel_launch(void* const* d_in, const int* in_sizes, int n_in,
                              void* d_out, int out_size, void* d_ws, size_t ws_size,
                              hipStream_t stream) {
    const float* P   = (const float*)d_in[0];
    const float* W1  = (const float*)d_in[1];
    const float* b1  = (const float*)d_in[2];
    const float* W2  = (const float*)d_in[3];
    const float* b2  = (const float*)d_in[4];
    const float* W3  = (const float*)d_in[5];
    const float* b3  = (const float*)d_in[6];
    const float* D1  = (const float*)d_in[7];
    const float* bD1 = (const float*)d_in[8];
    const float* D2  = (const float*)d_in[9];
    const float* bD2 = (const float*)d_in[10];
    const float* D3  = (const float*)d_in[11];
    const float* bD3 = (const float*)d_in[12];
    float* out = (float*)d_out;

    int B = in_sizes[0] / (NPTS * 3);
    hipLaunchKernelGGL(fused_kernel, dim3(B), dim3(TPB), 0, stream,
                       P, W1, b1, W2, b2, W3, b3, D1, bD1, D2, bD2, D3, bD3, out);
}

// Round 3
// 207.820 us; speedup vs baseline: 3.8463x; 3.8463x over previous
//
#include <hip/hip_runtime.h>

#define TPB 256
#define NW 4
#define NPTS 2000
#define M1C 100
#define M2C 5
#define KNN 20
#define CANDCAP 128   // knn scratch cap (knn1 cn<=~30 typ, knn2 cn<=100)
#define PCH 32        // producer chunks: 32*64 = 2048 >= 2000

typedef float v2f __attribute__((ext_vector_type(2)));

// Bitwise-exact squared distance matching numpy fp32 sequential sum:
// ((dx*dx + dy*dy) + dz*dz), no FMA contraction.
__device__ __forceinline__ float dist3(float px, float py, float pz,
                                       float qx, float qy, float qz) {
#pragma clang fp contract(off)
    float dx = px - qx, dy = py - qy, dz = pz - qz;
    return dx * dx + dy * dy + dz * dz;
}

// Packed pair variant: identical per-component op order (sub,mul,add,add),
// so each component is bitwise identical to dist3.
__device__ __forceinline__ v2f dist3p(v2f px, v2f py, v2f pz, v2f q0, v2f q1, v2f q2) {
#pragma clang fp contract(off)
    v2f dx = px - q0, dy = py - q1, dz = pz - q2;
    v2f ax = dx * dx;
    v2f ay = dy * dy;
    v2f az = dz * dz;
    return (ax + ay) + az;
}

// Fused wave64 (value,index) argmax, min-index tie-break, DPP chain.
#define ARGMAX_STEP(ctrl, rm)                                                        \
    do {                                                                             \
        float ov = __int_as_float(__builtin_amdgcn_update_dpp(                       \
            (int)0xff800000, __float_as_int(v), ctrl, rm, 0xf, false));              \
        int oi = __builtin_amdgcn_update_dpp(0x7fffffff, i, ctrl, rm, 0xf, false);   \
        bool take = (ov > v) || (ov == v && oi < i);                                 \
        v = take ? ov : v;                                                           \
        i = take ? oi : i;                                                           \
    } while (0)

__device__ __forceinline__ void wave_argmax(float& v, int& i) {
    ARGMAX_STEP(0x111, 0xf);
    ARGMAX_STEP(0x112, 0xf);
    ARGMAX_STEP(0x114, 0xf);
    ARGMAX_STEP(0x118, 0xf);
    ARGMAX_STEP(0x142, 0xa);
    ARGMAX_STEP(0x143, 0xc);
    v = __int_as_float(__builtin_amdgcn_readlane(__float_as_int(v), 63));
    i = __builtin_amdgcn_readlane(i, 63);
}

#define FMAX_STEP(ctrl, rm)                                                          \
    do {                                                                             \
        float _t = __int_as_float(__builtin_amdgcn_update_dpp(                       \
            (int)0xff800000, __float_as_int(x), ctrl, rm, 0xf, false));              \
        x = fmaxf(x, _t);                                                            \
    } while (0)

__device__ __forceinline__ float wave_fmax(float x) {
    FMAX_STEP(0x111, 0xf);
    FMAX_STEP(0x112, 0xf);
    FMAX_STEP(0x114, 0xf);
    FMAX_STEP(0x118, 0xf);
    FMAX_STEP(0x142, 0xa);
    FMAX_STEP(0x143, 0xc);
    return __int_as_float(__builtin_amdgcn_readlane(__float_as_int(x), 63));
}

// ============ Fused kernel ============
// R14 = R13 (single-wave FPS1 producer, zero cross-wave sync) with a
// SPILL-PROOF argmax: R13's tree scratch (v[32]+ki[32] = 64 VGPRs on top of
// the 128-VGPR point/min state) pushed the allocator into scratch spills
// (VGPR_Count=88 < 128 live floats -> 7300 cyc/iter). R14 replaces it with
// 4 running-argmax streams (8 VGPRs): chunk c updates stream c&3 with strict
// > (earliest chunk wins in-stream), then a 3-step cross-stream combine with
// explicit (val,idx) min-index tie-break — exact jnp.argmax first-occurrence
// semantics. Peak live ~150 VGPRs, well under the 512 available at 1
// wave/SIMD. Expected ~750 cyc/iter.
__global__ __launch_bounds__(TPB, 1) void fused_kernel(
    const float* __restrict__ P,
    const float* __restrict__ W1, const float* __restrict__ b1,
    const float* __restrict__ W2, const float* __restrict__ b2,
    const float* __restrict__ W3, const float* __restrict__ b3,
    const float* __restrict__ D1, const float* __restrict__ bD1,
    const float* __restrict__ D2, const float* __restrict__ bD2,
    const float* __restrict__ D3, const float* __restrict__ bD3,
    float* __restrict__ out)
{
    __shared__ float sx[NPTS], sy[NPTS], sz[NPTS];
    __shared__ float smpx[M1C], smpy[M1C], smpz[M1C];
    __shared__ float s2x[M2C], s2y[M2C], s2z[M2C];
    __shared__ float f1s[M1C][5];
    __shared__ float knd[NW][CANDCAP];
    __shared__ int   kni[NW][CANDCAP];
    __shared__ float vin[M2C][KNN][8];     // knn2 valid-candidate inputs
    __shared__ int prog;                   // highest published FPS1 sample index
    __shared__ float f2s[M2C][25];
    __shared__ float latent[45];
    __shared__ float decv[M2C][3];
    __shared__ float cfs[M2C][25];
    __shared__ float dec2s[M1C][3];
    __shared__ float cf2s[M1C][5];
    __shared__ float w2s[200], b2s[25], w3s[1260], b3s[45];

    const int b = blockIdx.x;
    const int tid = threadIdx.x;
    const int lane = tid & 63;
    const int wid = tid >> 6;

    const float R1SQ = (float)(0.3 * 0.3);   // f64 product then cast
    const float R2SQ = 1.0f;
    const float INVR1 = 1.0f / 0.3f;

    // ---- staging (all 4 waves) ----
    const float* Pb = P + (size_t)b * (NPTS * 3);
    for (int j = tid; j < NPTS; j += TPB) {
        sx[j] = Pb[3 * j + 0];
        sy[j] = Pb[3 * j + 1];
        sz[j] = Pb[3 * j + 2];
    }
    for (int t = tid; t < 200; t += TPB) w2s[t] = W2[t];
    for (int t = tid; t < 25; t += TPB) b2s[t] = b2[t];
    for (int t = tid; t < 1260; t += TPB) w3s[t] = W3[t];
    for (int t = tid; t < 45; t += TPB) b3s[t] = b3[t];
    if (tid == 0) prog = -1;
    __syncthreads();

    if (wid == 0) {
        // ================= producer: single-wave FPS1 =================
        // chunk k covers points [k*64, k*64+64); j = k*64 + lane is the
        // true linear point index.
        v2f px2[16], py2[16], pz2[16], mind2[16];
#pragma unroll
        for (int p = 0; p < 16; ++p) {
#pragma unroll
            for (int h = 0; h < 2; ++h) {
                int k = 2 * p + h;
                int j = k * 64 + lane;
                bool v = j < NPTS;
                int jc = v ? j : 0;
                px2[p][h] = v ? sx[jc] : 1e18f;
                py2[p][h] = v ? sy[jc] : 1e18f;
                pz2[p][h] = v ? sz[jc] : 1e18f;
                mind2[p][h] = v ? 1e10f : -1.0f;
            }
        }

        float qx = sx[0], qy = sy[0], qz = sz[0];
        for (int it = 0; it < M1C; ++it) {
            if (lane == 0) {
                smpx[it] = qx; smpy[it] = qy; smpz[it] = qz;
                __hip_atomic_store(&prog, it, __ATOMIC_RELEASE,
                                   __HIP_MEMORY_SCOPE_WORKGROUP);
            }
            if (it == M1C - 1) break;   // last sample: no further argmax needed

            v2f q0 = {qx, qx}, q1 = {qy, qy}, q2 = {qz, qz};
            // 4 running-argmax streams, 8 live regs total (bv[4], bk[4]).
            // Stream s holds chunks {c : c&3 == s}; strict > keeps the
            // earliest chunk within a stream (processed in increasing c).
            float bv[4] = {-1e30f, -1e30f, -1e30f, -1e30f};
            int   bk[4] = {0, 0, 0, 0};
#pragma unroll
            for (int p = 0; p < 16; ++p) {
                v2f d = dist3p(px2[p], py2[p], pz2[p], q0, q1, q2);
                v2f mm;
                mm[0] = fminf(mind2[p][0], d[0]);
                mm[1] = fminf(mind2[p][1], d[1]);
                mind2[p] = mm;
                {
                    const int c = 2 * p, s = c & 3;       // compile-time
                    bool t = mm[0] > bv[s];
                    bv[s] = t ? mm[0] : bv[s];
                    bk[s] = t ? c : bk[s];
                }
                {
                    const int c = 2 * p + 1, s = c & 3;   // compile-time
                    bool t = mm[1] > bv[s];
                    bv[s] = t ? mm[1] : bv[s];
                    bk[s] = t ? c : bk[s];
                }
            }
            // cross-stream combine with (val, idx) min-index tie-break
            float V = bv[0]; int K = bk[0];
            {
                bool t = (bv[1] > V) || (bv[1] == V && bk[1] < K);
                V = t ? bv[1] : V; K = t ? bk[1] : K;
            }
            {
                bool t = (bv[2] > V) || (bv[2] == V && bk[2] < K);
                V = t ? bv[2] : V; K = t ? bk[2] : K;
            }
            {
                bool t = (bv[3] > V) || (bv[3] == V && bk[3] < K);
                V = t ? bv[3] : V; K = t ? bk[3] : K;
            }
            float bvv = V;
            int bi = (K << 6) | lane;       // = linear point index
            wave_argmax(bvv, bi);           // broadcast (value,index), min-idx ties
            qx = sx[bi]; qy = sy[bi]; qz = sz[bi];   // uniform addr -> broadcast read
        }

        // ---- FPS2: 5 from 100 (same wave, in-LDS smp) ----
        {
            float ax = smpx[lane], ay = smpy[lane], az = smpz[lane];
            bool vb2 = lane < (M1C - 64);
            float bx2 = vb2 ? smpx[lane + 64] : 1e18f;
            float by2 = vb2 ? smpy[lane + 64] : 1e18f;
            float bz2 = vb2 ? smpz[lane + 64] : 1e18f;
            float m2a = 1e10f;
            float m2b = vb2 ? 1e10f : -1.0f;
            int last2 = 0;
            for (int it = 0; it < M2C; ++it) {
                float fx = smpx[last2], fy = smpy[last2], fz = smpz[last2];
                if (lane == 0) { s2x[it] = fx; s2y[it] = fy; s2z[it] = fz; }
                m2a = fminf(m2a, dist3(ax, ay, az, fx, fy, fz));
                m2b = fminf(m2b, dist3(bx2, by2, bz2, fx, fy, fz));
                float v = m2a; int i = lane;
                if (m2b > v) { v = m2b; i = lane + 64; }
                wave_argmax(v, i);
                last2 = i;
            }
        }
    } else {
        // ================= consumers: knn1 + MLP1 (waves 1-3) =================
        float rw1[15], rb1[5];
#pragma unroll
        for (int i = 0; i < 15; ++i) rw1[i] = W1[i];
#pragma unroll
        for (int i = 0; i < 5; ++i) rb1[i] = b1[i];

        for (int s = wid - 1; s < M1C; s += (NW - 1)) {
            // wait until producer published sample s
            while (__hip_atomic_load(&prog, __ATOMIC_ACQUIRE,
                                     __HIP_MEMORY_SCOPE_WORKGROUP) < s)
                __builtin_amdgcn_s_sleep(1);
            float qx = smpx[s], qy = smpy[s], qz = smpz[s];
            int cn = 0;
#pragma unroll 4
            for (int c = 0; c < 32; ++c) {
                int j = c * 64 + lane;
                float d = 0.0f; bool pred = false;
                if (j < NPTS) {
                    d = dist3(sx[j], sy[j], sz[j], qx, qy, qz);
                    pred = (d <= R1SQ);
                }
                unsigned long long mb = __ballot(pred);
                if (pred) {
                    int pos = cn + (int)__popcll(mb & ((1ull << lane) - 1ull));
                    if (pos < CANDCAP) { knd[wid][pos] = d; kni[wid][pos] = j; }
                }
                cn += (int)__popcll(mb);
            }
            if (cn > CANDCAP) cn = CANDCAP;  // P(Poisson λ≈14 > 128) ~ 1e-68
            float fmx[5];
#pragma unroll
            for (int f = 0; f < 5; ++f) fmx[f] = -1e30f;
            for (int t = lane; t < cn; t += 64) {
                float d = knd[wid][t]; int j = kni[wid][t];
                bool valid = true;
                if (cn > KNN) {
                    int rank = 0;
                    for (int u = 0; u < cn; ++u) {
                        float du = knd[wid][u]; int iu = kni[wid][u];
                        rank += (du < d || (du == d && iu < j)) ? 1 : 0;
                    }
                    valid = rank < KNN;   // replicates top_k stability (ties -> lower idx)
                }
                if (valid) {
                    float rx = (sx[j] - qx) * INVR1;
                    float ry = (sy[j] - qy) * INVR1;
                    float rz = (sz[j] - qz) * INVR1;
#pragma unroll
                    for (int f = 0; f < 5; ++f) {
                        float h = fmaf(rx, rw1[f], fmaf(ry, rw1[5 + f], fmaf(rz, rw1[10 + f], rb1[f])));
                        fmx[f] = fmaxf(fmx[f], fmaxf(h, 0.0f));
                    }
                }
            }
#pragma unroll
            for (int f = 0; f < 5; ++f) fmx[f] = wave_fmax(fmx[f]);
            if (lane == 0) {
#pragma unroll
                for (int f = 0; f < 5; ++f) f1s[s][f] = fmx[f];
            }
        }
    }
    __syncthreads();   // all 4 waves reach exactly once

    // ================= tail: knn2 + MLP2 (DPP-free), MLP3, decoder =================
    for (int s = wid; s < M2C; s += NW) {
        float qx2 = s2x[s], qy2 = s2y[s], qz2 = s2z[s];
        int cn = 0;
#pragma unroll
        for (int c = 0; c < 2; ++c) {
            int j = c * 64 + lane;
            float d = 0.0f; bool pred = false;
            if (j < M1C) {
                d = dist3(smpx[j], smpy[j], smpz[j], qx2, qy2, qz2);
                pred = (d <= R2SQ);
            }
            unsigned long long mb = __ballot(pred);
            if (pred) {
                int pos = cn + (int)__popcll(mb & ((1ull << lane) - 1ull));
                knd[wid][pos] = d; kni[wid][pos] = j;   // cn<=100<CANDCAP
            }
            cn += (int)__popcll(mb);
        }
        // build valid-candidate input vectors (order-independent for max)
        int nv = 0;
#pragma unroll
        for (int c = 0; c < 2; ++c) {
            int t = c * 64 + lane;
            bool valid = false;
            float in8[8];
            if (t < cn) {
                float d = knd[wid][t]; int j = kni[wid][t];
                valid = true;
                if (cn > KNN) {
                    int rank = 0;
                    for (int u = 0; u < cn; ++u) {
                        float du = knd[wid][u]; int iu = kni[wid][u];
                        rank += (du < d || (du == d && iu < j)) ? 1 : 0;
                    }
                    valid = rank < KNN;
                }
                if (valid) {
                    in8[0] = smpx[j] - qx2; in8[1] = smpy[j] - qy2; in8[2] = smpz[j] - qz2;
#pragma unroll
                    for (int f = 0; f < 5; ++f) in8[3 + f] = f1s[j][f];
                }
            }
            unsigned long long mb = __ballot(valid);
            if (valid) {
                int pos = nv + (int)__popcll(mb & ((1ull << lane) - 1ull));
#pragma unroll
                for (int i = 0; i < 8; ++i) vin[s][pos][i] = in8[i];   // nv<=20
            }
            nv += (int)__popcll(mb);
        }
        // feature-per-lane max (no DPP chains); nv >= 1 (sample in own ball)
        if (lane < 25) {
            float hmx = -1e30f;
            for (int c = 0; c < nv; ++c) {
                float h = b2s[lane];
#pragma unroll
                for (int i = 0; i < 8; ++i) h = fmaf(vin[s][c][i], w2s[i * 25 + lane], h);
                hmx = fmaxf(hmx, fmaxf(h, 0.0f));
            }
            f2s[s][lane] = hmx;
        }
    }
    __syncthreads();

    // ---- MLP3 + max-pool -> latent (45) ----
    if (wid == 0 && lane < 45) {
        float lm = -1e30f;
        for (int r = 0; r < M2C; ++r) {
            float h = b3s[lane];
            h = fmaf(s2x[r] * 0.5f, w3s[0 * 45 + lane], h);
            h = fmaf(s2y[r] * 0.5f, w3s[1 * 45 + lane], h);
            h = fmaf(s2z[r] * 0.5f, w3s[2 * 45 + lane], h);
#pragma unroll
            for (int i = 0; i < 25; ++i) h = fmaf(f2s[r][i], w3s[(3 + i) * 45 + lane], h);
            lm = fmaxf(lm, fmaxf(h, 0.0f));
        }
        latent[lane] = lm;
    }
    __syncthreads();

    // ---- decoder stage 1: latent @ D1 + bD1 -> (5, 28) ----
    for (int t = tid; t < 140; t += TPB) {
        float acc = bD1[t];
        for (int i = 0; i < 45; i++) acc = fmaf(latent[i], D1[i * 140 + t], acc);
        int r = t / 28, c = t % 28;
        if (c < 3) decv[r][c] = acc;
        else cfs[r][c - 3] = fmaxf(acc, 0.0f);
    }
    __syncthreads();

    // ---- decoder stage 2: cf @ D2 + bD2 -> (100, 8) ----
    for (int t = tid; t < 800; t += TPB) {
        int r = t / 160, c = t % 160;
        float acc = bD2[c];
        for (int i = 0; i < 25; i++) acc = fmaf(cfs[r][i], D2[i * 160 + c], acc);
        int g = r * 20 + c / 8, c8 = c % 8;
        if (c8 < 3) dec2s[g][c8] = acc;
        else cf2s[g][c8 - 3] = fmaxf(acc, 0.0f);
    }
    __syncthreads();

    // ---- decoder stage 3 + compose output ----
    float* outb = out + (size_t)b * (NPTS * 3);
    for (int t = tid; t < NPTS * 3; t += TPB) {
        int n = t / 3, c = t % 3;
        int g = n / 20;
        int m = n / 400;
        int r60 = (n % 20) * 3 + c;
        float acc = bD3[r60];
        for (int i = 0; i < 5; i++) acc = fmaf(cf2s[g][i], D3[i * 60 + r60], acc);
        // out = ((dec*R3 + dec2)*R2 + dec3)*R1, R2 = 1
        float val = ((decv[m][c] * 2.0f + dec2s[g][c]) + acc) * 0.3f;
        outb[t] = val;
    }
}

extern "C" void kernel_launch(void* const* d_in, const int* in_sizes, int n_in,
                              void* d_out, int out_size, void* d_ws, size_t ws_size,
                              hipStream_t stream) {
    const float* P   = (const float*)d_in[0];
    const float* W1  = (const float*)d_in[1];
    const float* b1  = (const float*)d_in[2];
    const float* W2  = (const float*)d_in[3];
    const float* b2  = (const float*)d_in[4];
    const float* W3  = (const float*)d_in[5];
    const float* b3  = (const float*)d_in[6];
    const float* D1  = (const float*)d_in[7];
    const float* bD1 = (const float*)d_in[8];
    const float* D2  = (const float*)d_in[9];
    const float* bD2 = (const float*)d_in[10];
    const float* D3  = (const float*)d_in[11];
    const float* bD3 = (const float*)d_in[12];
    float* out = (float*)d_out;

    int B = in_sizes[0] / (NPTS * 3);
    hipLaunchKernelGGL(fused_kernel, dim3(B), dim3(TPB), 0, stream,
                       P, W1, b1, W2, b2, W3, b3, D1, bD1, D2, bD2, D3, bD3, out);
}

// Round 4
// 205.739 us; speedup vs baseline: 3.8852x; 1.0101x over previous
//
#include <hip/hip_runtime.h>

#define TPB 256
#define NW 4
#define NPTS 2000
#define M1C 100
#define M2C 5
#define KNN 20
#define CANDCAP 128   // knn scratch cap (knn1 cn<=~30 typ, knn2 cn<=100)
#define PCH 32        // producer chunks: 32*64 = 2048 >= 2000

typedef float v2f __attribute__((ext_vector_type(2)));

// Bitwise-exact squared distance matching numpy fp32 sequential sum:
// ((dx*dx + dy*dy) + dz*dz), no FMA contraction.
__device__ __forceinline__ float dist3(float px, float py, float pz,
                                       float qx, float qy, float qz) {
#pragma clang fp contract(off)
    float dx = px - qx, dy = py - qy, dz = pz - qz;
    return dx * dx + dy * dy + dz * dz;
}

// Packed pair variant: identical per-component op order (sub,mul,add,add),
// so each component is bitwise identical to dist3.
__device__ __forceinline__ v2f dist3p(v2f px, v2f py, v2f pz, v2f q0, v2f q1, v2f q2) {
#pragma clang fp contract(off)
    v2f dx = px - q0, dy = py - q1, dz = pz - q2;
    v2f ax = dx * dx;
    v2f ay = dy * dy;
    v2f az = dz * dz;
    return (ax + ay) + az;
}

// Fused wave64 (value,index) argmax, min-index tie-break, DPP chain.
#define ARGMAX_STEP(ctrl, rm)                                                        \
    do {                                                                             \
        float ov = __int_as_float(__builtin_amdgcn_update_dpp(                       \
            (int)0xff800000, __float_as_int(v), ctrl, rm, 0xf, false));              \
        int oi = __builtin_amdgcn_update_dpp(0x7fffffff, i, ctrl, rm, 0xf, false);   \
        bool take = (ov > v) || (ov == v && oi < i);                                 \
        v = take ? ov : v;                                                           \
        i = take ? oi : i;                                                           \
    } while (0)

__device__ __forceinline__ void wave_argmax(float& v, int& i) {
    ARGMAX_STEP(0x111, 0xf);
    ARGMAX_STEP(0x112, 0xf);
    ARGMAX_STEP(0x114, 0xf);
    ARGMAX_STEP(0x118, 0xf);
    ARGMAX_STEP(0x142, 0xa);
    ARGMAX_STEP(0x143, 0xc);
    v = __int_as_float(__builtin_amdgcn_readlane(__float_as_int(v), 63));
    i = __builtin_amdgcn_readlane(i, 63);
}

#define FMAX_STEP(ctrl, rm)                                                          \
    do {                                                                             \
        float _t = __int_as_float(__builtin_amdgcn_update_dpp(                       \
            (int)0xff800000, __float_as_int(x), ctrl, rm, 0xf, false));              \
        x = fmaxf(x, _t);                                                            \
    } while (0)

__device__ __forceinline__ float wave_fmax(float x) {
    FMAX_STEP(0x111, 0xf);
    FMAX_STEP(0x112, 0xf);
    FMAX_STEP(0x114, 0xf);
    FMAX_STEP(0x118, 0xf);
    FMAX_STEP(0x142, 0xa);
    FMAX_STEP(0x143, 0xc);
    return __int_as_float(__builtin_amdgcn_readlane(__float_as_int(x), 63));
}

// X-macro over the 16 v2f chunk-pairs (32 chunks of 64 points).
#define PTS16(X) X(0) X(1) X(2) X(3) X(4) X(5) X(6) X(7) \
                 X(8) X(9) X(10) X(11) X(12) X(13) X(14) X(15)

// ============ Fused kernel ============
// R15 = R14 with the producer's point-cloud state in 64 INDIVIDUALLY-NAMED
// v2f variables instead of v2f[16] arrays. R13/R14 post-mortem: SROA promotes
// v2f[4] (32B, R11) but NOT v2f[16] (128B) -> allocas stayed in scratch ->
// VGPR_Count=84 < the 128 live floats needed -> ~1100 cyc/iter serial scratch
// refills. Named variables are plain SSA values; the allocator must place
// them in VGPRs (expect VGPR_Count >= 150; 256 available at 1 wave/EU).
// Everything else is byte-identical to R14.
__global__ __launch_bounds__(TPB, 1) void fused_kernel(
    const float* __restrict__ P,
    const float* __restrict__ W1, const float* __restrict__ b1,
    const float* __restrict__ W2, const float* __restrict__ b2,
    const float* __restrict__ W3, const float* __restrict__ b3,
    const float* __restrict__ D1, const float* __restrict__ bD1,
    const float* __restrict__ D2, const float* __restrict__ bD2,
    const float* __restrict__ D3, const float* __restrict__ bD3,
    float* __restrict__ out)
{
    __shared__ float sx[NPTS], sy[NPTS], sz[NPTS];
    __shared__ float smpx[M1C], smpy[M1C], smpz[M1C];
    __shared__ float s2x[M2C], s2y[M2C], s2z[M2C];
    __shared__ float f1s[M1C][5];
    __shared__ float knd[NW][CANDCAP];
    __shared__ int   kni[NW][CANDCAP];
    __shared__ float vin[M2C][KNN][8];     // knn2 valid-candidate inputs
    __shared__ int prog;                   // highest published FPS1 sample index
    __shared__ float f2s[M2C][25];
    __shared__ float latent[45];
    __shared__ float decv[M2C][3];
    __shared__ float cfs[M2C][25];
    __shared__ float dec2s[M1C][3];
    __shared__ float cf2s[M1C][5];
    __shared__ float w2s[200], b2s[25], w3s[1260], b3s[45];

    const int b = blockIdx.x;
    const int tid = threadIdx.x;
    const int lane = tid & 63;
    const int wid = tid >> 6;

    const float R1SQ = (float)(0.3 * 0.3);   // f64 product then cast
    const float R2SQ = 1.0f;
    const float INVR1 = 1.0f / 0.3f;

    // ---- staging (all 4 waves) ----
    const float* Pb = P + (size_t)b * (NPTS * 3);
    for (int j = tid; j < NPTS; j += TPB) {
        sx[j] = Pb[3 * j + 0];
        sy[j] = Pb[3 * j + 1];
        sz[j] = Pb[3 * j + 2];
    }
    for (int t = tid; t < 200; t += TPB) w2s[t] = W2[t];
    for (int t = tid; t < 25; t += TPB) b2s[t] = b2[t];
    for (int t = tid; t < 1260; t += TPB) w3s[t] = W3[t];
    for (int t = tid; t < 45; t += TPB) b3s[t] = b3[t];
    if (tid == 0) prog = -1;
    __syncthreads();

    if (wid == 0) {
        // ================= producer: single-wave FPS1 =================
        // chunk k covers points [k*64, k*64+64); j = k*64 + lane is the
        // true linear point index.
#define DECLP(p) v2f px##p, py##p, pz##p, mind##p;
        PTS16(DECLP)
#undef DECLP

#define INITP(p) {                                                        \
        const int j0 = (2*(p)) * 64 + lane;                               \
        const int j1 = (2*(p)+1) * 64 + lane;                             \
        const bool v0 = j0 < NPTS, v1 = j1 < NPTS;                        \
        const int a0 = v0 ? j0 : 0, a1 = v1 ? j1 : 0;                     \
        px##p[0] = v0 ? sx[a0] : 1e18f;  px##p[1] = v1 ? sx[a1] : 1e18f;  \
        py##p[0] = v0 ? sy[a0] : 1e18f;  py##p[1] = v1 ? sy[a1] : 1e18f;  \
        pz##p[0] = v0 ? sz[a0] : 1e18f;  pz##p[1] = v1 ? sz[a1] : 1e18f;  \
        mind##p[0] = v0 ? 1e10f : -1.0f; mind##p[1] = v1 ? 1e10f : -1.0f; \
    }
        PTS16(INITP)
#undef INITP

        float qx = sx[0], qy = sy[0], qz = sz[0];
        for (int it = 0; it < M1C; ++it) {
            if (lane == 0) {
                smpx[it] = qx; smpy[it] = qy; smpz[it] = qz;
                __hip_atomic_store(&prog, it, __ATOMIC_RELEASE,
                                   __HIP_MEMORY_SCOPE_WORKGROUP);
            }
            if (it == M1C - 1) break;   // last sample: no further argmax needed

            v2f q0 = {qx, qx}, q1 = {qy, qy}, q2 = {qz, qz};
            // 4 running-argmax streams (constant-indexed 4-arrays: SROA-safe).
            // Stream s holds chunks {c : c&3 == s}; strict > keeps the
            // earliest chunk within a stream (processed in increasing c).
            float bv[4] = {-1e30f, -1e30f, -1e30f, -1e30f};
            int   bk[4] = {0, 0, 0, 0};
#define STEPP(p) {                                                        \
        v2f d = dist3p(px##p, py##p, pz##p, q0, q1, q2);                  \
        v2f mm;                                                           \
        mm[0] = fminf(mind##p[0], d[0]);                                  \
        mm[1] = fminf(mind##p[1], d[1]);                                  \
        mind##p = mm;                                                     \
        { const int c0 = 2*(p), s0 = c0 & 3;                              \
          bool t0 = mm[0] > bv[s0];                                       \
          bv[s0] = t0 ? mm[0] : bv[s0];                                   \
          bk[s0] = t0 ? c0 : bk[s0]; }                                    \
        { const int c1 = 2*(p)+1, s1 = c1 & 3;                            \
          bool t1 = mm[1] > bv[s1];                                       \
          bv[s1] = t1 ? mm[1] : bv[s1];                                   \
          bk[s1] = t1 ? c1 : bk[s1]; }                                    \
    }
            PTS16(STEPP)
#undef STEPP
            // cross-stream combine with (val, idx) min-index tie-break
            float V = bv[0]; int K = bk[0];
            {
                bool t = (bv[1] > V) || (bv[1] == V && bk[1] < K);
                V = t ? bv[1] : V; K = t ? bk[1] : K;
            }
            {
                bool t = (bv[2] > V) || (bv[2] == V && bk[2] < K);
                V = t ? bv[2] : V; K = t ? bk[2] : K;
            }
            {
                bool t = (bv[3] > V) || (bv[3] == V && bk[3] < K);
                V = t ? bv[3] : V; K = t ? bk[3] : K;
            }
            float bvv = V;
            int bi = (K << 6) | lane;       // = linear point index
            wave_argmax(bvv, bi);           // broadcast (value,index), min-idx ties
            qx = sx[bi]; qy = sy[bi]; qz = sz[bi];   // uniform addr -> broadcast read
        }

        // ---- FPS2: 5 from 100 (same wave, in-LDS smp) ----
        {
            float ax = smpx[lane], ay = smpy[lane], az = smpz[lane];
            bool vb2 = lane < (M1C - 64);
            float bx2 = vb2 ? smpx[lane + 64] : 1e18f;
            float by2 = vb2 ? smpy[lane + 64] : 1e18f;
            float bz2 = vb2 ? smpz[lane + 64] : 1e18f;
            float m2a = 1e10f;
            float m2b = vb2 ? 1e10f : -1.0f;
            int last2 = 0;
            for (int it = 0; it < M2C; ++it) {
                float fx = smpx[last2], fy = smpy[last2], fz = smpz[last2];
                if (lane == 0) { s2x[it] = fx; s2y[it] = fy; s2z[it] = fz; }
                m2a = fminf(m2a, dist3(ax, ay, az, fx, fy, fz));
                m2b = fminf(m2b, dist3(bx2, by2, bz2, fx, fy, fz));
                float v = m2a; int i = lane;
                if (m2b > v) { v = m2b; i = lane + 64; }
                wave_argmax(v, i);
                last2 = i;
            }
        }
    } else {
        // ================= consumers: knn1 + MLP1 (waves 1-3) =================
        float rw1[15], rb1[5];
#pragma unroll
        for (int i = 0; i < 15; ++i) rw1[i] = W1[i];
#pragma unroll
        for (int i = 0; i < 5; ++i) rb1[i] = b1[i];

        for (int s = wid - 1; s < M1C; s += (NW - 1)) {
            // wait until producer published sample s
            while (__hip_atomic_load(&prog, __ATOMIC_ACQUIRE,
                                     __HIP_MEMORY_SCOPE_WORKGROUP) < s)
                __builtin_amdgcn_s_sleep(1);
            float qx = smpx[s], qy = smpy[s], qz = smpz[s];
            int cn = 0;
#pragma unroll 4
            for (int c = 0; c < 32; ++c) {
                int j = c * 64 + lane;
                float d = 0.0f; bool pred = false;
                if (j < NPTS) {
                    d = dist3(sx[j], sy[j], sz[j], qx, qy, qz);
                    pred = (d <= R1SQ);
                }
                unsigned long long mb = __ballot(pred);
                if (pred) {
                    int pos = cn + (int)__popcll(mb & ((1ull << lane) - 1ull));
                    if (pos < CANDCAP) { knd[wid][pos] = d; kni[wid][pos] = j; }
                }
                cn += (int)__popcll(mb);
            }
            if (cn > CANDCAP) cn = CANDCAP;  // P(Poisson λ≈14 > 128) ~ 1e-68
            float fmx[5];
#pragma unroll
            for (int f = 0; f < 5; ++f) fmx[f] = -1e30f;
            for (int t = lane; t < cn; t += 64) {
                float d = knd[wid][t]; int j = kni[wid][t];
                bool valid = true;
                if (cn > KNN) {
                    int rank = 0;
                    for (int u = 0; u < cn; ++u) {
                        float du = knd[wid][u]; int iu = kni[wid][u];
                        rank += (du < d || (du == d && iu < j)) ? 1 : 0;
                    }
                    valid = rank < KNN;   // replicates top_k stability (ties -> lower idx)
                }
                if (valid) {
                    float rx = (sx[j] - qx) * INVR1;
                    float ry = (sy[j] - qy) * INVR1;
                    float rz = (sz[j] - qz) * INVR1;
#pragma unroll
                    for (int f = 0; f < 5; ++f) {
                        float h = fmaf(rx, rw1[f], fmaf(ry, rw1[5 + f], fmaf(rz, rw1[10 + f], rb1[f])));
                        fmx[f] = fmaxf(fmx[f], fmaxf(h, 0.0f));
                    }
                }
            }
#pragma unroll
            for (int f = 0; f < 5; ++f) fmx[f] = wave_fmax(fmx[f]);
            if (lane == 0) {
#pragma unroll
                for (int f = 0; f < 5; ++f) f1s[s][f] = fmx[f];
            }
        }
    }
    __syncthreads();   // all 4 waves reach exactly once

    // ================= tail: knn2 + MLP2 (DPP-free), MLP3, decoder =================
    for (int s = wid; s < M2C; s += NW) {
        float qx2 = s2x[s], qy2 = s2y[s], qz2 = s2z[s];
        int cn = 0;
#pragma unroll
        for (int c = 0; c < 2; ++c) {
            int j = c * 64 + lane;
            float d = 0.0f; bool pred = false;
            if (j < M1C) {
                d = dist3(smpx[j], smpy[j], smpz[j], qx2, qy2, qz2);
                pred = (d <= R2SQ);
            }
            unsigned long long mb = __ballot(pred);
            if (pred) {
                int pos = cn + (int)__popcll(mb & ((1ull << lane) - 1ull));
                knd[wid][pos] = d; kni[wid][pos] = j;   // cn<=100<CANDCAP
            }
            cn += (int)__popcll(mb);
        }
        // build valid-candidate input vectors (order-independent for max)
        int nv = 0;
#pragma unroll
        for (int c = 0; c < 2; ++c) {
            int t = c * 64 + lane;
            bool valid = false;
            float in8[8];
            if (t < cn) {
                float d = knd[wid][t]; int j = kni[wid][t];
                valid = true;
                if (cn > KNN) {
                    int rank = 0;
                    for (int u = 0; u < cn; ++u) {
                        float du = knd[wid][u]; int iu = kni[wid][u];
                        rank += (du < d || (du == d && iu < j)) ? 1 : 0;
                    }
                    valid = rank < KNN;
                }
                if (valid) {
                    in8[0] = smpx[j] - qx2; in8[1] = smpy[j] - qy2; in8[2] = smpz[j] - qz2;
#pragma unroll
                    for (int f = 0; f < 5; ++f) in8[3 + f] = f1s[j][f];
                }
            }
            unsigned long long mb = __ballot(valid);
            if (valid) {
                int pos = nv + (int)__popcll(mb & ((1ull << lane) - 1ull));
#pragma unroll
                for (int i = 0; i < 8; ++i) vin[s][pos][i] = in8[i];   // nv<=20
            }
            nv += (int)__popcll(mb);
        }
        // feature-per-lane max (no DPP chains); nv >= 1 (sample in own ball)
        if (lane < 25) {
            float hmx = -1e30f;
            for (int c = 0; c < nv; ++c) {
                float h = b2s[lane];
#pragma unroll
                for (int i = 0; i < 8; ++i) h = fmaf(vin[s][c][i], w2s[i * 25 + lane], h);
                hmx = fmaxf(hmx, fmaxf(h, 0.0f));
            }
            f2s[s][lane] = hmx;
        }
    }
    __syncthreads();

    // ---- MLP3 + max-pool -> latent (45) ----
    if (wid == 0 && lane < 45) {
        float lm = -1e30f;
        for (int r = 0; r < M2C; ++r) {
            float h = b3s[lane];
            h = fmaf(s2x[r] * 0.5f, w3s[0 * 45 + lane], h);
            h = fmaf(s2y[r] * 0.5f, w3s[1 * 45 + lane], h);
            h = fmaf(s2z[r] * 0.5f, w3s[2 * 45 + lane], h);
#pragma unroll
            for (int i = 0; i < 25; ++i) h = fmaf(f2s[r][i], w3s[(3 + i) * 45 + lane], h);
            lm = fmaxf(lm, fmaxf(h, 0.0f));
        }
        latent[lane] = lm;
    }
    __syncthreads();

    // ---- decoder stage 1: latent @ D1 + bD1 -> (5, 28) ----
    for (int t = tid; t < 140; t += TPB) {
        float acc = bD1[t];
        for (int i = 0; i < 45; i++) acc = fmaf(latent[i], D1[i * 140 + t], acc);
        int r = t / 28, c = t % 28;
        if (c < 3) decv[r][c] = acc;
        else cfs[r][c - 3] = fmaxf(acc, 0.0f);
    }
    __syncthreads();

    // ---- decoder stage 2: cf @ D2 + bD2 -> (100, 8) ----
    for (int t = tid; t < 800; t += TPB) {
        int r = t / 160, c = t % 160;
        float acc = bD2[c];
        for (int i = 0; i < 25; i++) acc = fmaf(cfs[r][i], D2[i * 160 + c], acc);
        int g = r * 20 + c / 8, c8 = c % 8;
        if (c8 < 3) dec2s[g][c8] = acc;
        else cf2s[g][c8 - 3] = fmaxf(acc, 0.0f);
    }
    __syncthreads();

    // ---- decoder stage 3 + compose output ----
    float* outb = out + (size_t)b * (NPTS * 3);
    for (int t = tid; t < NPTS * 3; t += TPB) {
        int n = t / 3, c = t % 3;
        int g = n / 20;
        int m = n / 400;
        int r60 = (n % 20) * 3 + c;
        float acc = bD3[r60];
        for (int i = 0; i < 5; i++) acc = fmaf(cf2s[g][i], D3[i * 60 + r60], acc);
        // out = ((dec*R3 + dec2)*R2 + dec3)*R1, R2 = 1
        float val = ((decv[m][c] * 2.0f + dec2s[g][c]) + acc) * 0.3f;
        outb[t] = val;
    }
}

extern "C" void kernel_launch(void* const* d_in, const int* in_sizes, int n_in,
                              void* d_out, int out_size, void* d_ws, size_t ws_size,
                              hipStream_t stream) {
    const float* P   = (const float*)d_in[0];
    const float* W1  = (const float*)d_in[1];
    const float* b1  = (const float*)d_in[2];
    const float* W2  = (const float*)d_in[3];
    const float* b2  = (const float*)d_in[4];
    const float* W3  = (const float*)d_in[5];
    const float* b3  = (const float*)d_in[6];
    const float* D1  = (const float*)d_in[7];
    const float* bD1 = (const float*)d_in[8];
    const float* D2  = (const float*)d_in[9];
    const float* bD2 = (const float*)d_in[10];
    const float* D3  = (const float*)d_in[11];
    const float* bD3 = (const float*)d_in[12];
    float* out = (float*)d_out;

    int B = in_sizes[0] / (NPTS * 3);
    hipLaunchKernelGGL(fused_kernel, dim3(B), dim3(TPB), 0, stream,
                       P, W1, b1, W2, b2, W3, b3, D1, bD1, D2, bD2, D3, bD3, out);
}